// Round 5
// baseline (598.583 us; speedup 1.0000x reference)
//
#include <hip/hip_runtime.h>

typedef __bf16 bf16x8 __attribute__((ext_vector_type(8)));
typedef __bf16 bf16x4 __attribute__((ext_vector_type(4)));
typedef float floatx4 __attribute__((ext_vector_type(4)));

__device__ __forceinline__ __bf16 f2bf(float f) {
  union { float f; unsigned u; } x; x.f = f;
  unsigned r = (x.u + 0x7FFFu + ((x.u >> 16) & 1u)) >> 16;
  union { unsigned short u; __bf16 b; } o; o.u = (unsigned short)r; return o.b;
}
__device__ __forceinline__ float bf2f(__bf16 b) {
  union { unsigned short u; __bf16 b; } i; i.b = b;
  union { unsigned u; float f; } y; y.u = ((unsigned)i.u) << 16; return y.f;
}

#define MFMA16(a, b, c) __builtin_amdgcn_mfma_f32_16x16x32_bf16(a, b, c, 0, 0, 0)

// Swizzle for stride-192 bf16 LDS tiles (verified in round 3).
#define SW(r, c) ((r) * 192 + ((c) ^ (((r) & 7) << 3)))
// Swizzle for stride-768 bf16 LDS tiles (prep_xf staging).
#define SWX(r, c) ((r) * 768 + ((c) ^ (((r) & 7) << 3)))

// ---------------- prep: weights -> FRAGMENT-MAJOR bf16 layout ----------------
// Element (nt, kk32, lane, e) = W[k = kk32*32 + (lane>>4)*8 + e][n = nt*16 + (lane&15)].
__global__ __launch_bounds__(256) void prep_weights(
    const float* __restrict__ W1, const float* __restrict__ WQ,
    const float* __restrict__ WK, const float* __restrict__ WV,
    const float* __restrict__ W2,
    __bf16* __restrict__ w1f, __bf16* __restrict__ wqf,
    __bf16* __restrict__ wkf, __bf16* __restrict__ wvf,
    __bf16* __restrict__ w2f) {
  int i = blockIdx.x * 256 + threadIdx.x;
  if (i < 147456) {  // W1: K=768 (kk32 0..23), N=192 (nt 0..11)
    int e = i & 7, lane = (i >> 3) & 63, rest = i >> 9;
    int kk32 = rest % 24, nt = rest / 24;
    int n = nt * 16 + (lane & 15), k = kk32 * 32 + (lane >> 4) * 8 + e;
    w1f[i] = f2bf(W1[k * 192 + n]); return;
  }
  i -= 147456;
  if (i < 36864) {   // WQ: K=192, N=192
    int e = i & 7, lane = (i >> 3) & 63, rest = i >> 9;
    int kk32 = rest % 6, nt = rest / 6;
    int n = nt * 16 + (lane & 15), k = kk32 * 32 + (lane >> 4) * 8 + e;
    wqf[i] = f2bf(WQ[k * 192 + n]); return;
  }
  i -= 36864;
  if (i < 36864) {
    int e = i & 7, lane = (i >> 3) & 63, rest = i >> 9;
    int kk32 = rest % 6, nt = rest / 6;
    int n = nt * 16 + (lane & 15), k = kk32 * 32 + (lane >> 4) * 8 + e;
    wkf[i] = f2bf(WK[k * 192 + n]); return;
  }
  i -= 36864;
  if (i < 36864) {
    int e = i & 7, lane = (i >> 3) & 63, rest = i >> 9;
    int kk32 = rest % 6, nt = rest / 6;
    int n = nt * 16 + (lane & 15), k = kk32 * 32 + (lane >> 4) * 8 + e;
    wvf[i] = f2bf(WV[k * 192 + n]); return;
  }
  i -= 36864;
  if (i < 147456) {  // W2: K=192 (kk32 0..5), N=768 (nt 0..47)
    int e = i & 7, lane = (i >> 3) & 63, rest = i >> 9;
    int kk32 = rest % 6, nt = rest / 6;
    int n = nt * 16 + (lane & 15), k = kk32 * 32 + (lane >> 4) * 8 + e;
    w2f[i] = f2bf(W2[k * 768 + n]); return;
  }
}

// x -> fragment-major bf16, through LDS: coalesced global reads AND writes.
__global__ __launch_bounds__(256) void prep_xf(
    const float* __restrict__ x, __bf16* __restrict__ xf) {
  __shared__ __align__(16) __bf16 tile[24576];  // 32x768, SWX-swizzled
  int p = blockIdx.x;
  int tid = threadIdx.x;
  const float* xb = x + (size_t)p * 24576;
#pragma unroll
  for (int i = 0; i < 24; ++i) {
    int idx = i * 256 + tid;             // float4 index (6144 total)
    float4 v = ((const float4*)xb)[idx];
    int row = idx / 192, c4 = (idx % 192) * 4;
    bf16x4 b;
    b[0] = f2bf(v.x); b[1] = f2bf(v.y); b[2] = f2bf(v.z); b[3] = f2bf(v.w);
    *(bf16x4*)(&tile[SWX(row, c4)]) = b;
  }
  __syncthreads();
  __bf16* dst = xf + (size_t)p * 24576;
#pragma unroll
  for (int w = 0; w < 12; ++w) {
    int j = w * 256 + tid;               // fragment-of-8 index (3072 total)
    int lane = j & 63, rest = j >> 6;    // rest 0..47
    int kk32 = rest % 24, mt = rest / 24;
    int row = mt * 16 + (lane & 15);
    int col = kk32 * 32 + ((lane >> 4) & 3) * 8;
    *(bf16x8*)(dst + j * 8) = *(const bf16x8*)(&tile[SWX(row, col)]);
  }
}

// xpos tables: [32][192] each (repeat-2 applied)
__global__ __launch_bounds__(256) void prep_tables(
    float* __restrict__ cq, float* __restrict__ sq,
    float* __restrict__ ck, float* __restrict__ sk) {
  int i = blockIdx.x * 256 + threadIdx.x;
  if (i >= 32 * 96) return;
  int s = i / 96, f = i % 96;
  float base = (2.f * f + 0.4f * 192.f) / (1.4f * 192.f);
  float scale = powf(base, (float)s / 512.f);
  float invf = powf(10000.f, -(float)f / 96.f);
  float ang = (float)s * invf;
  float sn = sinf(ang), cs = cosf(ang);
  int o = s * 192 + 2 * f;
  cq[o] = cs * scale; cq[o + 1] = cs * scale;
  sq[o] = sn * scale; sq[o + 1] = sn * scale;
  ck[o] = cs / scale; ck[o + 1] = cs / scale;
  sk[o] = sn / scale; sk[o + 1] = sn / scale;
}

// ---------------- main fused kernel: one WG (4 waves) per TWO sequences (M=64) ----------------
// Every weight fragment load feeds 4 MFMAs (2 seqs x 2 row-tiles); block count halved.
template <bool USE_XF>
__global__ __launch_bounds__(256, 2) void retnet_main(
    const float* __restrict__ x, const float* __restrict__ b1,
    const float* __restrict__ b2, const float* __restrict__ ln_g,
    const float* __restrict__ ln_b,
    const __bf16* __restrict__ w1f, const __bf16* __restrict__ wqf,
    const __bf16* __restrict__ wkf, const __bf16* __restrict__ wvf,
    const __bf16* __restrict__ w2f,
    const float* __restrict__ cq, const float* __restrict__ sq,
    const float* __restrict__ ck, const float* __restrict__ sk,
    const __bf16* __restrict__ xf, float* __restrict__ out) {
  // LDS 79872 B -> 2 blocks/CU:
  //   h0/h1   @0/12288      (SW)   Vt0/Vt1 overlay after P3 ([d][s] stride 32)
  //   Q0/Q1   @24576/36864  (SW)   ret0/ret1 overlay after P4 (SW)
  //   K0/K1   @49152/61440  (SW)
  //   att0/1  @73728/76800  (32x48, stride 48)
  __shared__ __align__(16) char smem[79872];
  __bf16* h[2] = {(__bf16*)smem, (__bf16*)(smem + 12288)};
  __bf16* Q[2] = {(__bf16*)(smem + 24576), (__bf16*)(smem + 36864)};
  __bf16* K[2] = {(__bf16*)(smem + 49152), (__bf16*)(smem + 61440)};
  __bf16* att[2] = {(__bf16*)(smem + 73728), (__bf16*)(smem + 76800)};
  __bf16** Vt = h;    // overlay
  __bf16** ret = Q;   // overlay

  const int tid = threadIdx.x;
  const int wv = tid >> 6;     // 0..3 (owns 48 cols of d=192 for both seqs)
  const int lane = tid & 63;
  const int l16 = lane & 15;
  const int quad = lane >> 4;
  const int kof = quad * 8;
  const int wv3 = wv * 3;
  const int p = blockIdx.x;    // pair index; seqs 2p, 2p+1
  const float* xblk[2] = {x + (size_t)(2 * p) * 24576, x + (size_t)(2 * p + 1) * 24576};

  // ---- Phase 1: x_down = xr @ W1 + b1 (M=64,N=192,K=768) -> h[ss] ----
  {
    floatx4 acc[2][2][3] = {};
    if (USE_XF) {
      const __bf16* xf0 = xf + (size_t)(2 * p) * 24576;
#pragma unroll 4
      for (int kk32 = 0; kk32 < 24; ++kk32) {
        bf16x8 a[2][2];
#pragma unroll
        for (int ss = 0; ss < 2; ++ss) {
          a[ss][0] = *(const bf16x8*)(xf0 + ss * 24576 + kk32 * 512 + lane * 8);
          a[ss][1] = *(const bf16x8*)(xf0 + ss * 24576 + 12288 + kk32 * 512 + lane * 8);
        }
#pragma unroll
        for (int t = 0; t < 3; ++t) {
          bf16x8 bb = *(const bf16x8*)(w1f + (size_t)((wv3 + t) * 24 + kk32) * 512 + lane * 8);
          acc[0][0][t] = MFMA16(a[0][0], bb, acc[0][0][t]);
          acc[0][1][t] = MFMA16(a[0][1], bb, acc[0][1][t]);
          acc[1][0][t] = MFMA16(a[1][0], bb, acc[1][0][t]);
          acc[1][1][t] = MFMA16(a[1][1], bb, acc[1][1][t]);
        }
      }
    } else {
#pragma unroll 2
      for (int kk = 0; kk < 768; kk += 32) {
        bf16x8 a[2][2];
#pragma unroll
        for (int ss = 0; ss < 2; ++ss)
#pragma unroll
          for (int m = 0; m < 2; ++m) {
            const float* ar = xblk[ss] + (m * 16 + l16) * 768 + kk + kof;
            float4 f0 = *(const float4*)ar;
            float4 f1 = *(const float4*)(ar + 4);
            bf16x8 v;
            v[0] = f2bf(f0.x); v[1] = f2bf(f0.y); v[2] = f2bf(f0.z); v[3] = f2bf(f0.w);
            v[4] = f2bf(f1.x); v[5] = f2bf(f1.y); v[6] = f2bf(f1.z); v[7] = f2bf(f1.w);
            a[ss][m] = v;
          }
        int kk32 = kk >> 5;
#pragma unroll
        for (int t = 0; t < 3; ++t) {
          bf16x8 bb = *(const bf16x8*)(w1f + (size_t)((wv3 + t) * 24 + kk32) * 512 + lane * 8);
          acc[0][0][t] = MFMA16(a[0][0], bb, acc[0][0][t]);
          acc[0][1][t] = MFMA16(a[0][1], bb, acc[0][1][t]);
          acc[1][0][t] = MFMA16(a[1][0], bb, acc[1][0][t]);
          acc[1][1][t] = MFMA16(a[1][1], bb, acc[1][1][t]);
        }
      }
    }
#pragma unroll
    for (int ss = 0; ss < 2; ++ss)
#pragma unroll
      for (int m = 0; m < 2; ++m)
#pragma unroll
        for (int t = 0; t < 3; ++t) {
          int col = wv * 48 + t * 16 + l16;
          float bias = b1[col];
#pragma unroll
          for (int r = 0; r < 4; ++r) {
            int row = m * 16 + quad * 4 + r;
            h[ss][SW(row, col)] = f2bf(acc[ss][m][t][r] + bias);
          }
        }
  }
  __syncthreads();

  // ---- Phase 2: LayerNorm rows of h in place (8 lanes/row, 24 elems; 2 seqs serial) ----
  {
    int r = tid >> 3, g = tid & 7;
#pragma unroll
    for (int ss = 0; ss < 2; ++ss) {
      float vals[24]; float s = 0.f, s2 = 0.f;
#pragma unroll
      for (int j = 0; j < 24; ++j) {
        int c = g * 24 + j;
        float v = bf2f(h[ss][SW(r, c)]);
        vals[j] = v; s += v; s2 += v * v;
      }
#pragma unroll
      for (int o = 1; o < 8; o <<= 1) { s += __shfl_xor(s, o); s2 += __shfl_xor(s2, o); }
      float mu = s * (1.f / 192.f);
      float var = s2 * (1.f / 192.f) - mu * mu;
      float rstd = rsqrtf(var + 1e-5f);
#pragma unroll
      for (int j = 0; j < 24; ++j) {
        int c = g * 24 + j;
        h[ss][SW(r, c)] = f2bf((vals[j] - mu) * rstd * ln_g[c] + ln_b[c]);
      }
    }
  }
  __syncthreads();

  // ---- Phase 3: Q/K/V = h @ W (both seqs share B-frags); xpos on Q,K; V kept in regs ----
  auto gemm_h2 = [&](const __bf16* __restrict__ Wf, floatx4 (&a)[2][2][3]) {
#pragma unroll
    for (int kk = 0; kk < 6; ++kk) {
      bf16x8 a00 = *(const bf16x8*)(h[0] + SW(l16, kk * 32 + kof));
      bf16x8 a01 = *(const bf16x8*)(h[0] + SW(16 + l16, kk * 32 + kof));
      bf16x8 a10 = *(const bf16x8*)(h[1] + SW(l16, kk * 32 + kof));
      bf16x8 a11 = *(const bf16x8*)(h[1] + SW(16 + l16, kk * 32 + kof));
#pragma unroll
      for (int t = 0; t < 3; ++t) {
        bf16x8 bb = *(const bf16x8*)(Wf + (size_t)((wv3 + t) * 6 + kk) * 512 + lane * 8);
        a[0][0][t] = MFMA16(a00, bb, a[0][0][t]);
        a[0][1][t] = MFMA16(a01, bb, a[0][1][t]);
        a[1][0][t] = MFMA16(a10, bb, a[1][0][t]);
        a[1][1][t] = MFMA16(a11, bb, a[1][1][t]);
      }
    }
  };
  bf16x4 vv[2][2][3];  // V fragments held in registers until Vt overlay is safe
  {
    floatx4 aq[2][2][3] = {};
    gemm_h2(wqf, aq);
#pragma unroll
    for (int ss = 0; ss < 2; ++ss)
#pragma unroll
      for (int m = 0; m < 2; ++m)
#pragma unroll
        for (int t = 0; t < 3; ++t) {
          int col = wv * 48 + t * 16 + l16;
#pragma unroll
          for (int r = 0; r < 4; ++r) {
            int row = m * 16 + quad * 4 + r;
            float v = aq[ss][m][t][r];
            float pr = __shfl_xor(v, 1);
            float o = v * cq[row * 192 + col] + ((lane & 1) ? pr : -pr) * sq[row * 192 + col];
            Q[ss][SW(row, col)] = f2bf(o);
          }
        }
  }
  {
    floatx4 ak[2][2][3] = {};
    gemm_h2(wkf, ak);
#pragma unroll
    for (int ss = 0; ss < 2; ++ss)
#pragma unroll
      for (int m = 0; m < 2; ++m)
#pragma unroll
        for (int t = 0; t < 3; ++t) {
          int col = wv * 48 + t * 16 + l16;
#pragma unroll
          for (int r = 0; r < 4; ++r) {
            int row = m * 16 + quad * 4 + r;
            float v = ak[ss][m][t][r];
            float pr = __shfl_xor(v, 1);
            float o = v * ck[row * 192 + col] + ((lane & 1) ? pr : -pr) * sk[row * 192 + col];
            K[ss][SW(row, col)] = f2bf(o);
          }
        }
  }
  {
    floatx4 av[2][2][3] = {};
    gemm_h2(wvf, av);
#pragma unroll
    for (int ss = 0; ss < 2; ++ss)
#pragma unroll
      for (int m = 0; m < 2; ++m)
#pragma unroll
        for (int t = 0; t < 3; ++t)
#pragma unroll
          for (int r = 0; r < 4; ++r) vv[ss][m][t][r] = f2bf(av[ss][m][t][r]);
  }
  __syncthreads();  // all h reads done -> Vt may overlay h

  // ---- Phase 4: write Vt (overlay h); att = (Q @ K^T) * decay per seq ----
  {
#pragma unroll
    for (int ss = 0; ss < 2; ++ss)
#pragma unroll
      for (int m = 0; m < 2; ++m)
#pragma unroll
        for (int t = 0; t < 3; ++t) {
          int col = wv * 48 + t * 16 + l16;
          *(bf16x4*)(Vt[ss] + col * 32 + m * 16 + quad * 4) = vv[ss][m][t];  // [d][s]
        }
    int mt = wv >> 1, nt = wv & 1;
#pragma unroll
    for (int ss = 0; ss < 2; ++ss) {
      floatx4 a4 = {0.f, 0.f, 0.f, 0.f};
#pragma unroll
      for (int kk = 0; kk < 6; ++kk) {
        bf16x8 aq = *(const bf16x8*)(Q[ss] + SW(mt * 16 + l16, kk * 32 + kof));
        bf16x8 bk = *(const bf16x8*)(K[ss] + SW(nt * 16 + l16, kk * 32 + kof));
        a4 = MFMA16(aq, bk, a4);
      }
#pragma unroll
      for (int r = 0; r < 4; ++r) {
        int i = mt * 16 + quad * 4 + r;
        int j = nt * 16 + l16;
        float v = (i >= j) ? a4[r] * exp2f((float)(j - i)) : 0.f;
        att[ss][i * 48 + j] = f2bf(v);
      }
    }
  }
  __syncthreads();

  // ---- Phase 5: ret = att @ V per seq -> ret (overlays Q) ----
  {
#pragma unroll
    for (int ss = 0; ss < 2; ++ss) {
      floatx4 ar[2][3] = {};
      bf16x8 a0 = *(const bf16x8*)(att[ss] + l16 * 48 + kof);
      bf16x8 a1 = *(const bf16x8*)(att[ss] + (16 + l16) * 48 + kof);
#pragma unroll
      for (int t = 0; t < 3; ++t) {
        bf16x8 bb = *(const bf16x8*)(Vt[ss] + (wv * 48 + t * 16 + l16) * 32 + kof);
        ar[0][t] = MFMA16(a0, bb, ar[0][t]);
        ar[1][t] = MFMA16(a1, bb, ar[1][t]);
      }
#pragma unroll
      for (int m = 0; m < 2; ++m)
#pragma unroll
        for (int t = 0; t < 3; ++t) {
          int col = wv * 48 + t * 16 + l16;
#pragma unroll
          for (int r = 0; r < 4; ++r) {
            int row = m * 16 + quad * 4 + r;
            ret[ss][SW(row, col)] = f2bf(ar[m][t][r]);
          }
        }
    }
  }
  __syncthreads();

  // ---- Phase 6: out = x + ret @ W2 + b2 (both seqs share w2f B-frags) ----
  {
    bf16x8 af[2][2][6];
#pragma unroll
    for (int ss = 0; ss < 2; ++ss)
#pragma unroll
      for (int k6 = 0; k6 < 6; ++k6) {
        af[ss][0][k6] = *(const bf16x8*)(ret[ss] + SW(l16, k6 * 32 + kof));
        af[ss][1][k6] = *(const bf16x8*)(ret[ss] + SW(16 + l16, k6 * 32 + kof));
      }
#pragma unroll
    for (int g = 0; g < 4; ++g) {
      floatx4 ao[2][2][3] = {};
#pragma unroll
      for (int k6 = 0; k6 < 6; ++k6)
#pragma unroll
        for (int t = 0; t < 3; ++t) {
          bf16x8 bb = *(const bf16x8*)(w2f + (size_t)((wv * 12 + g * 3 + t) * 6 + k6) * 512 + lane * 8);
          ao[0][0][t] = MFMA16(af[0][0][k6], bb, ao[0][0][t]);
          ao[0][1][t] = MFMA16(af[0][1][k6], bb, ao[0][1][t]);
          ao[1][0][t] = MFMA16(af[1][0][k6], bb, ao[1][0][t]);
          ao[1][1][t] = MFMA16(af[1][1][k6], bb, ao[1][1][t]);
        }
#pragma unroll
      for (int ss = 0; ss < 2; ++ss)
#pragma unroll
        for (int m = 0; m < 2; ++m)
#pragma unroll
          for (int t = 0; t < 3; ++t) {
            int col = wv * 192 + g * 48 + t * 16 + l16;
            float bias = b2[col];
#pragma unroll
            for (int r = 0; r < 4; ++r) {
              int row = m * 16 + quad * 4 + r;
              size_t gi = (size_t)(2 * p + ss) * 24576 + row * 768 + col;
              out[gi] = xblk[ss][row * 768 + col] + ao[ss][m][t][r] + bias;
            }
          }
    }
  }
}

extern "C" void kernel_launch(void* const* d_in, const int* in_sizes, int n_in,
                              void* d_out, int out_size, void* d_ws, size_t ws_size,
                              hipStream_t stream) {
  const float* x = (const float*)d_in[0];
  const float* W1 = (const float*)d_in[1];
  const float* b1 = (const float*)d_in[2];
  const float* W2 = (const float*)d_in[3];
  const float* b2 = (const float*)d_in[4];
  const float* lng = (const float*)d_in[5];
  const float* lnb = (const float*)d_in[6];
  const float* WQ = (const float*)d_in[7];
  const float* WK = (const float*)d_in[8];
  const float* WV = (const float*)d_in[9];
  float* out = (float*)d_out;

  char* ws = (char*)d_ws;
  __bf16* w1f = (__bf16*)(ws + 0);
  __bf16* wqf = (__bf16*)(ws + 294912);
  __bf16* wkf = (__bf16*)(ws + 368640);
  __bf16* wvf = (__bf16*)(ws + 442368);
  __bf16* w2f = (__bf16*)(ws + 516096);
  float* cq = (float*)(ws + 811008);
  float* sq = cq + 6144;
  float* ck = sq + 6144;
  float* sk = ck + 6144;
  const size_t xf_off = 909312;                      // 16B-aligned
  const size_t xf_bytes = 77070336;                  // 196*256*768 bf16
  bool use_xf = (ws_size >= xf_off + xf_bytes);
  __bf16* xfp = (__bf16*)(ws + xf_off);

  hipLaunchKernelGGL(prep_weights, dim3(1584), dim3(256), 0, stream,
                     W1, WQ, WK, WV, W2, w1f, wqf, wkf, wvf, w2f);
  hipLaunchKernelGGL(prep_tables, dim3(12), dim3(256), 0, stream, cq, sq, ck, sk);
  if (use_xf) {
    hipLaunchKernelGGL(prep_xf, dim3(1568), dim3(256), 0, stream, x, xfp);
    hipLaunchKernelGGL((retnet_main<true>), dim3(784), dim3(256), 0, stream,
                       x, b1, b2, lng, lnb, w1f, wqf, wkf, wvf, w2f,
                       cq, sq, ck, sk, (const __bf16*)xfp, out);
  } else {
    hipLaunchKernelGGL((retnet_main<false>), dim3(784), dim3(256), 0, stream,
                       x, b1, b2, lng, lnb, w1f, wqf, wkf, wvf, w2f,
                       cq, sq, ck, sk, (const __bf16*)nullptr, out);
  }
}